// Round 16
// baseline (949.171 us; speedup 1.0000x reference)
//
#include <hip/hip_runtime.h>

#define TLEN 512
#define HDIM 64
#define NB   8     // real batches per block (MFMA cols 8-15 duplicate 0-7)
#define NTH  768   // 12 waves: 0-3 L0(w_hh0), 4-7 L1a(w_ih1), 8-11 L1b(w_hh1)
#define GRID 256   // all 256 CUs busy
#define XPAD 516   // xs row stride

typedef __attribute__((ext_vector_type(8))) short bf16x8;
typedef __attribute__((ext_vector_type(4))) float f32x4;

__device__ __forceinline__ float sigm(float x){ return __fdividef(1.f, 1.f+__expf(-x)); }
__device__ __forceinline__ float tanh_(float x){ return 1.f - __fdividef(2.f, __expf(2.f*x)+1.f); }

__device__ __forceinline__ short bf16rn(float f){
    unsigned u = __float_as_uint(f);
    u = (u + 0x7FFFu + ((u >> 16) & 1u)) >> 16;
    return (short)u;
}
__device__ __forceinline__ float bf2f(short s){
    return __uint_as_float(((unsigned)(unsigned short)s) << 16);
}
__device__ __forceinline__ float bf2f_u(unsigned lo16){
    return __uint_as_float(lo16 << 16);
}

// One 16-row x 64-k A-tile as hi/lo bf16 fragments for mfma_16x16x32.
// Lane l supplies A[rowbase + (l&15)][khalf*32 + (l>>4)*8 + e].  (verified r7/r12)
__device__ __forceinline__ void loadA(const float* __restrict__ W, int rowbase, int lane,
                                      bf16x8& hi0, bf16x8& lo0, bf16x8& hi1, bf16x8& lo1)
{
    const int row = rowbase + (lane & 15);
    const int q   = lane >> 4;
    const float* p = W + row * HDIM + q * 8;
    #pragma unroll
    for (int e = 0; e < 8; ++e) {
        const float f0 = p[e];
        const float f1 = p[32 + e];
        const short a0 = bf16rn(f0); hi0[e] = a0; lo0[e] = bf16rn(f0 - bf2f(a0));
        const short a1 = bf16rn(f1); hi1[e] = a1; lo1[e] = bf16rn(f1 - bf2f(a1));
    }
}

#define MFMA __builtin_amdgcn_mfma_f32_16x16x32_bf16

// 12-wave 3-group split: each wave holds ONE matrix (64 VGPR of weights),
// total demand ~120-125/wave -> fits the allocator's 128 budget honestly
// (r12-r15: 2-matrix L1 waves demanded ~200 -> forced spill at the stubborn
// 128 target; attributes couldn't move it).
__global__ __launch_bounds__(NTH)
void lstm2_ws3(const float* __restrict__ x,
               const float* __restrict__ w_ih0,
               const float* __restrict__ w_hh0,
               const float* __restrict__ b_ih0,
               const float* __restrict__ b_hh0,
               const float* __restrict__ w_ih1,
               const float* __restrict__ w_hh1,
               const float* __restrict__ b_ih1,
               const float* __restrict__ b_hh1,
               const float* __restrict__ fc_w,
               const float* __restrict__ fc_b,
               float* __restrict__ out)
{
    // h fragment store: [buf][hi/lo][kh][q][batch][e]  (h[b][kh*32+q*8+e])
    __shared__ float xs[16 * XPAD];            // 33 KB (rows 8-15 duplicate 0-7)
    __shared__ short h1f[2][2][2][4][16][8];   // 16 KB
    __shared__ short h2f[2][2][2][4][16][8];   // 16 KB
    __shared__ float pa2[2][4][4][4][16][4];   // 32 KB  [pp][w4][g][q][r15][r]
    __shared__ float h2last[16][HDIM];         // 4 KB   -> total ~101 KB: 1 blk/CU

    const int tid  = threadIdx.x;
    const int wid  = tid >> 6;
    const int grp  = wid >> 2;    // 0=L0, 1=L1a, 2=L1b
    const int w4   = wid & 3;
    const int lane = tid & 63;
    const int q    = lane >> 4;
    const int r15  = lane & 15;   // batch column (8-15 duplicate 0-7)
    const int b0   = blockIdx.x * NB;
    const bool lohalf = (r15 < 8);

    // ---- stage x (coalesced float4); rows 8-15 duplicate rows 0-7 ----
    {
        const float4* xg = (const float4*)(x + (size_t)b0 * TLEN);
        for (int idx = tid; idx < 16 * TLEN / 4; idx += NTH) {
            const int row = idx >> 7;
            const int col = idx & 127;
            *(float4*)&xs[row * XPAD + col * 4] = xg[(row & 7) * 128 + col];
        }
    }
    for (int idx = tid; idx < 8192; idx += NTH) {   // zero BOTH buffers of both h stores
        ((short*)h1f)[idx] = 0;
        ((short*)h2f)[idx] = 0;
    }

    // ---- per-wave weight fragments: exactly ONE matrix per wave ----
    const int U0 = w4 * 16;
    const float* Wm = (grp == 0) ? w_hh0 : (grp == 1) ? w_ih1 : w_hh1;
    bf16x8 Mh0[4], Ml0[4], Mh1[4], Ml1[4];
    #pragma unroll
    for (int g = 0; g < 4; ++g)
        loadA(Wm, g * 64 + U0, lane, Mh0[g], Ml0[g], Mh1[g], Ml1[g]);

    // update-phase constants (lane owns rows rA=lohalf?0:2 and rB=rA+1 of its q-quad)
    const int rA = lohalf ? 0 : 2;
    f32x4 b2A = {0,0,0,0}, b2B = {0,0,0,0}, wxA = {0,0,0,0}, wxB = {0,0,0,0};
    if (grp == 0) {
        #pragma unroll
        for (int g = 0; g < 4; ++g) {
            const int rowA = g * 64 + U0 + q * 4 + rA;
            b2A[g] = b_ih0[rowA] + b_hh0[rowA];     wxA[g] = w_ih0[rowA];
            b2B[g] = b_ih0[rowA+1] + b_hh0[rowA+1]; wxB[g] = w_ih0[rowA+1];
        }
    } else if (grp == 2) {
        #pragma unroll
        for (int g = 0; g < 4; ++g) {
            const int rowA = g * 64 + U0 + q * 4 + rA;
            b2A[g] = b_ih1[rowA] + b_hh1[rowA];
            b2B[g] = b_ih1[rowA+1] + b_hh1[rowA+1];
        }
    }
    // h-write scatter coords (verified r12): unit u = U0+4q+r
    const int kh = w4 >> 1;
    const int qp = (2 * w4 + (q >> 1)) & 3;
    const int eo = (q & 1) * 4;
    float ccA = 0.f, ccB = 0.f;
    int p = 0;

    __syncthreads();

    // Skew: iter i -> L0: h1(i); L1a: pa(i)=w_ih1.h1(i-1); L1b: h2(i-2).
    // One barrier per iteration; pa double-buffered (write i&1, read (i&1)^1).
    for (int i = 0; i <= TLEN + 1; ++i) {
        const bool active = (grp == 0) ? (i < TLEN)
                          : (grp == 1) ? (i >= 1 && i <= TLEN)
                                       : (i >= 2);
        if (active) {
            f32x4 acc[4];
            if (grp == 0) {
                const bf16x8 Bh0 = *(const bf16x8*)&h1f[p][0][0][q][r15][0];
                const bf16x8 Bh1 = *(const bf16x8*)&h1f[p][0][1][q][r15][0];
                const bf16x8 Bl0 = *(const bf16x8*)&h1f[p][1][0][q][r15][0];
                const bf16x8 Bl1 = *(const bf16x8*)&h1f[p][1][1][q][r15][0];
                #pragma unroll
                for (int g = 0; g < 4; ++g) {
                    f32x4 a = {0,0,0,0};
                    a = MFMA(Mh0[g], Bh0, a, 0, 0, 0);
                    a = MFMA(Ml0[g], Bh0, a, 0, 0, 0);
                    a = MFMA(Mh0[g], Bl0, a, 0, 0, 0);
                    f32x4 b = {0,0,0,0};
                    b = MFMA(Mh1[g], Bh1, b, 0, 0, 0);
                    b = MFMA(Ml1[g], Bh1, b, 0, 0, 0);
                    b = MFMA(Mh1[g], Bl1, b, 0, 0, 0);
                    #pragma unroll
                    for (int r = 0; r < 4; ++r) acc[g][r] = a[r] + b[r];
                }
            } else if (grp == 1) {
                const bf16x8 Bh0 = *(const bf16x8*)&h1f[p][0][0][q][r15][0];
                const bf16x8 Bh1 = *(const bf16x8*)&h1f[p][0][1][q][r15][0];
                const bf16x8 Bl0 = *(const bf16x8*)&h1f[p][1][0][q][r15][0];
                const bf16x8 Bl1 = *(const bf16x8*)&h1f[p][1][1][q][r15][0];
                #pragma unroll
                for (int g = 0; g < 4; ++g) {
                    f32x4 a = {0,0,0,0};
                    a = MFMA(Mh0[g], Bh0, a, 0, 0, 0);
                    a = MFMA(Ml0[g], Bh0, a, 0, 0, 0);
                    a = MFMA(Mh0[g], Bl0, a, 0, 0, 0);
                    f32x4 b = {0,0,0,0};
                    b = MFMA(Mh1[g], Bh1, b, 0, 0, 0);
                    b = MFMA(Ml1[g], Bh1, b, 0, 0, 0);
                    b = MFMA(Mh1[g], Bl1, b, 0, 0, 0);
                    #pragma unroll
                    for (int r = 0; r < 4; ++r) acc[g][r] = a[r] + b[r];
                }
                // publish partials for L1b (same lane coords -> linear, conflict-free)
                #pragma unroll
                for (int g = 0; g < 4; ++g)
                    *(f32x4*)&pa2[i & 1][w4][g][q][r15][0] = acc[g];
            } else {
                const bf16x8 Bh0 = *(const bf16x8*)&h2f[p][0][0][q][r15][0];
                const bf16x8 Bh1 = *(const bf16x8*)&h2f[p][0][1][q][r15][0];
                const bf16x8 Bl0 = *(const bf16x8*)&h2f[p][1][0][q][r15][0];
                const bf16x8 Bl1 = *(const bf16x8*)&h2f[p][1][1][q][r15][0];
                #pragma unroll
                for (int g = 0; g < 4; ++g) {
                    f32x4 a = {0,0,0,0};
                    a = MFMA(Mh0[g], Bh0, a, 0, 0, 0);
                    a = MFMA(Ml0[g], Bh0, a, 0, 0, 0);
                    a = MFMA(Mh0[g], Bl0, a, 0, 0, 0);
                    f32x4 b = {0,0,0,0};
                    b = MFMA(Mh1[g], Bh1, b, 0, 0, 0);
                    b = MFMA(Ml1[g], Bh1, b, 0, 0, 0);
                    b = MFMA(Mh1[g], Bl1, b, 0, 0, 0);
                    const f32x4 pv = *(const f32x4*)&pa2[(i & 1) ^ 1][w4][g][q][r15][0];
                    #pragma unroll
                    for (int r = 0; r < 4; ++r) acc[g][r] = a[r] + b[r] + pv[r];
                }
            }

            // ---- update phase (L0 and L1b only) ----
            if (grp != 1) {
                const float xv = (grp == 0) ? xs[r15 * XPAD + i] : 0.f;
                float hvA, hvB;
                {
                    const float gi = sigm (acc[0][rA]   + b2A[0] + wxA[0] * xv);
                    const float gf = sigm (acc[1][rA]   + b2A[1] + wxA[1] * xv);
                    const float gg = tanh_(acc[2][rA]   + b2A[2] + wxA[2] * xv);
                    const float go = sigm (acc[3][rA]   + b2A[3] + wxA[3] * xv);
                    ccA = fmaf(gf, ccA, gi * gg);
                    hvA = go * tanh_(ccA);
                }
                {
                    const float gi = sigm (acc[0][rA+1] + b2B[0] + wxB[0] * xv);
                    const float gf = sigm (acc[1][rA+1] + b2B[1] + wxB[1] * xv);
                    const float gg = tanh_(acc[2][rA+1] + b2B[2] + wxB[2] * xv);
                    const float go = sigm (acc[3][rA+1] + b2B[3] + wxB[3] * xv);
                    ccB = fmaf(gf, ccB, gi * gg);
                    hvB = go * tanh_(ccB);
                }
                const short sA = bf16rn(hvA), lA = bf16rn(hvA - bf2f(sA));
                const short sB = bf16rn(hvB), lB = bf16rn(hvB - bf2f(sB));
                const unsigned ownH = (unsigned)(unsigned short)sA | ((unsigned)(unsigned short)sB << 16);
                const unsigned ownL = (unsigned)(unsigned short)lA | ((unsigned)(unsigned short)lB << 16);
                const unsigned othH = (unsigned)__shfl_xor((int)ownH, 8, 64);
                const unsigned othL = (unsigned)__shfl_xor((int)ownL, 8, 64);
                const unsigned h01 = lohalf ? ownH : othH;
                const unsigned h23 = lohalf ? othH : ownH;
                const unsigned l01 = lohalf ? ownL : othL;
                const unsigned l23 = lohalf ? othL : ownL;
                if (grp == 0) {
                    *(uint2*)&h1f[p ^ 1][0][kh][qp][r15][eo] = (uint2){h01, h23};
                    *(uint2*)&h1f[p ^ 1][1][kh][qp][r15][eo] = (uint2){l01, l23};
                } else {
                    *(uint2*)&h2f[p ^ 1][0][kh][qp][r15][eo] = (uint2){h01, h23};
                    *(uint2*)&h2f[p ^ 1][1][kh][qp][r15][eo] = (uint2){l01, l23};
                    if (i == TLEN + 1) {
                        f32x4 hv;
                        hv[0] = bf2f_u(h01 & 0xFFFFu) + bf2f_u(l01 & 0xFFFFu);
                        hv[1] = bf2f_u(h01 >> 16)     + bf2f_u(l01 >> 16);
                        hv[2] = bf2f_u(h23 & 0xFFFFu) + bf2f_u(l23 & 0xFFFFu);
                        hv[3] = bf2f_u(h23 >> 16)     + bf2f_u(l23 >> 16);
                        *(f32x4*)&h2last[r15][U0 + q * 4] = hv;
                    }
                }
            }
        }
        __syncthreads();   // uniform: every wave, every iteration
        p ^= 1;
    }

    // ======== final FC (threads 0..511): thread (b = tid>>5, s = tid&31) ========
    if (tid < 512) {
        const int fb = tid >> 5, fs = tid & 31;   // fb 0..15; 8-15 are duplicates
        float psum = fc_w[fs] * h2last[fb][fs] + fc_w[fs + 32] * h2last[fb][fs + 32];
        psum += __shfl_xor(psum, 16);
        psum += __shfl_xor(psum, 8);
        psum += __shfl_xor(psum, 4);
        psum += __shfl_xor(psum, 2);
        psum += __shfl_xor(psum, 1);
        if (fs == 0 && fb < NB) out[b0 + fb] = psum + fc_b[0];
    }
}

extern "C" void kernel_launch(void* const* d_in, const int* in_sizes, int n_in,
                              void* d_out, int out_size, void* d_ws, size_t ws_size,
                              hipStream_t stream) {
    const float* xp     = (const float*)d_in[0];
    const float* w_ih0  = (const float*)d_in[1];
    const float* w_hh0  = (const float*)d_in[2];
    const float* b_ih0  = (const float*)d_in[3];
    const float* b_hh0  = (const float*)d_in[4];
    const float* w_ih1  = (const float*)d_in[5];
    const float* w_hh1  = (const float*)d_in[6];
    const float* b_ih1  = (const float*)d_in[7];
    const float* b_hh1  = (const float*)d_in[8];
    const float* fc_w   = (const float*)d_in[9];
    const float* fc_b   = (const float*)d_in[10];
    float* outp = (float*)d_out;

    lstm2_ws3<<<dim3(GRID), dim3(NTH), 0, stream>>>(
        xp, w_ih0, w_hh0, b_ih0, b_hh0,
        w_ih1, w_hh1, b_ih1, b_hh1, fc_w, fc_b, outp);
}